// Round 9
// baseline (122.724 us; speedup 1.0000x reference)
//
#include <hip/hip_runtime.h>
#include <hip/hip_bf16.h>
#include <math.h>

// Laplacian-pyramid L1 loss, (2,1,64,256,256), 5 levels, sigma=1 (9-tap), scipy-reflect.
// loss = sum_l mean |lap_pyramid(input-target)[l]| (linearity of the pyramid).
// 12 plain launches (no cross-block sync; agent-scope fences proven catastrophic r5/r7):
//   k1l0(+bf16 DIFF + x>=132 |diff| partials) -> k2s0 -> {k1s,k2s} x levels 1..4
//   -> k4pz (all levels, z-PAIRED blocks, float4 staging) -> kreduce.

struct GW { float w[9]; float A, B; };

__device__ __forceinline__ int ridx(int p, int n) {
    // scipy 'reflect' (symmetric) for power-of-two n; valid for p >= -2n
    int m = 2 * n;
    int q = (p + m) & (m - 1);
    return (q < n) ? q : (m - 1 - q);
}

__device__ __forceinline__ float block_sum256(float v) {
    #pragma unroll
    for (int off = 32; off > 0; off >>= 1) v += __shfl_down(v, off, 64);
    __shared__ float wp[4];
    int tid = threadIdx.x;
    if ((tid & 63) == 0) wp[tid >> 6] = v;
    __syncthreads();
    return wp[0] + wp[1] + wp[2] + wp[3];
}

// ---------------------------------------------------------------------------
// k1l0: level-0 fused W+H gaussian of (in - tg) -> T1 (even y,x).
// Also: bf16 DIFF for x<132 (k4pz reads only there), and the x>=132 |diff| sum
// (up==0 there) as per-block partials P[0..1024).
template<bool WDIFF>
__global__ __launch_bounds__(256)
void k1l0(const float* __restrict__ in, const float* __restrict__ tg,
          float* __restrict__ T1, __hip_bfloat16* __restrict__ DIFF,
          float* __restrict__ P, GW g)
{
    const int H = 256, W = 256, Wd = 128;
    const int x0d = blockIdx.x * 64, y0d = blockIdx.y * 16, slice = blockIdx.z;
    __shared__ float raw[40][136];
    __shared__ float mid[40][64];
    const size_t in_off  = (size_t)slice * H * W;
    const size_t out_off = (size_t)slice * 128 * 128;
    const int tid = threadIdx.x;
    const int gy0 = 2*y0d - 4, gx0 = 2*x0d - 4;
    for (int i = tid; i < 40*32; i += 256) {
        int rr = i >> 5, c4 = (i & 31) + 1;
        int gy = ridx(gy0 + rr, H);
        size_t base = in_off + (size_t)gy * W + gx0 + 4*c4;
        float4 v = *(const float4*)(in + base);
        float4 b = *(const float4*)(tg + base);
        v.x -= b.x; v.y -= b.y; v.z -= b.z; v.w -= b.w;
        *(float4*)&raw[rr][4*c4] = v;
    }
    for (int i = tid; i < 40*8; i += 256) {
        int rr = i >> 3, j = i & 7;
        int cc = (j < 4) ? j : (128 + j);
        int gy = ridx(gy0 + rr, H);
        int gx = ridx(gx0 + cc, W);
        size_t idx = in_off + (size_t)gy * W + gx;
        raw[rr][cc] = in[idx] - tg[idx];
    }
    __syncthreads();
    if (WDIFF) {
        if (blockIdx.x == 0) {
            // full-res x in [0,128): all needed by k4pz
            for (int i = tid; i < 32*128; i += 256) {
                int r = i >> 7, c = i & 127;
                DIFF[in_off + (size_t)(2*y0d + r) * W + c] =
                    __float2bfloat16(raw[4 + r][4 + c]);
            }
        } else {
            // x in [128,132) only (k4pz skips x>=132)
            for (int i = tid; i < 32*4; i += 256) {
                int r = i >> 2, c = i & 3;
                DIFF[in_off + (size_t)(2*y0d + r) * W + 128 + c] =
                    __float2bfloat16(raw[4 + r][4 + c]);
            }
        }
    }
    if (blockIdx.x == 1) {
        // x >= 132 loss contribution: sum |diff| over raw rows 4..36, cols 8..132
        float lsum = 0.f;
        for (int i = tid; i < 32*124; i += 256) {
            int r = i / 124, c = i - r*124;
            lsum += fabsf(raw[4 + r][8 + c]);
        }
        float tot = block_sum256(lsum);
        if (tid == 0)
            P[blockIdx.y + 8*blockIdx.z] = tot * (1.f / 8388608.f);
    }
    for (int i = tid; i < 40*64; i += 256) {
        int rr = i >> 6, c = i & 63;
        float s = 0.f;
        #pragma unroll
        for (int k = 0; k < 9; ++k) s = fmaf(g.w[k], raw[rr][2*c + k], s);
        mid[rr][c] = s;
    }
    __syncthreads();
    {
        int r = tid >> 6, c = tid & 63;
        int ox = x0d + c;
        #pragma unroll
        for (int j = 0; j < 4; ++j) {
            int oy = y0d + r*4 + j;
            int rb = 2*(r*4 + j);
            float s = 0.f;
            #pragma unroll
            for (int k = 0; k < 9; ++k) s = fmaf(g.w[k], mid[rb + k][c], s);
            T1[out_off + (size_t)oy * Wd + ox] = s;
        }
    }
}

// ---------------------------------------------------------------------------
// k2s: D-axis gaussian + batch(2) reflect mix at even z. One float4/elem.
__global__ __launch_bounds__(256)
void k2s(const float* __restrict__ Tin, float* __restrict__ Cout,
         int D, int Dd, int M4, GW g)
{
    long i = (long)blockIdx.x * 256 + threadIdx.x;
    if (i >= (long)Dd * M4) return;
    int zd = (int)(i / M4);
    int q  = (int)(i - (long)zd * M4);
    const float4* T = (const float4*)Tin;
    float4* O = (float4*)Cout;
    float4 s0 = {0,0,0,0}, s1 = {0,0,0,0};
    #pragma unroll
    for (int k = 0; k < 9; ++k) {
        int zp = 2*zd - 4 + k;
        int zk = (zp >= 0 && zp < D) ? zp : ridx(zp, D);
        float4 a = T[(size_t)zk * M4 + q];
        float4 b = T[(size_t)(D + zk) * M4 + q];
        s0.x = fmaf(g.w[k], a.x, s0.x); s0.y = fmaf(g.w[k], a.y, s0.y);
        s0.z = fmaf(g.w[k], a.z, s0.z); s0.w = fmaf(g.w[k], a.w, s0.w);
        s1.x = fmaf(g.w[k], b.x, s1.x); s1.y = fmaf(g.w[k], b.y, s1.y);
        s1.z = fmaf(g.w[k], b.z, s1.z); s1.w = fmaf(g.w[k], b.w, s1.w);
    }
    float4 o0, o1;
    o0.x = g.A*s0.x + g.B*s1.x; o0.y = g.A*s0.y + g.B*s1.y;
    o0.z = g.A*s0.z + g.B*s1.z; o0.w = g.A*s0.w + g.B*s1.w;
    o1.x = g.B*s0.x + g.A*s1.x; o1.y = g.B*s0.y + g.A*s1.y;
    o1.z = g.B*s0.z + g.A*s1.z; o1.w = g.B*s0.w + g.A*s1.w;
    O[(size_t)zd * M4 + q] = o0;
    O[(size_t)(Dd + zd) * M4 + q] = o1;
}

// ---------------------------------------------------------------------------
// k1s: fused W+H gaussian on one (H,W) slice, even (y,x) -> (Hd,Wd).
__global__ __launch_bounds__(256)
void k1s(const float* __restrict__ inA, float* __restrict__ out,
         int H, int W, int Hd, int Wd, GW g)
{
    const int x0d = blockIdx.x * 64, y0d = blockIdx.y * 16, slice = blockIdx.z;
    __shared__ float raw[40][136];
    __shared__ float mid[40][64];
    const size_t in_off  = (size_t)slice * H * W;
    const size_t out_off = (size_t)slice * Hd * Wd;
    const int tid = threadIdx.x;
    const int gy0 = 2*y0d - 4, gx0 = 2*x0d - 4;
    if (2*x0d + 127 < W) {
        for (int i = tid; i < 40*32; i += 256) {
            int rr = i >> 5, c4 = (i & 31) + 1;
            int gy = ridx(gy0 + rr, H);
            *(float4*)&raw[rr][4*c4] =
                *(const float4*)(inA + in_off + (size_t)gy * W + gx0 + 4*c4);
        }
        for (int i = tid; i < 40*8; i += 256) {
            int rr = i >> 3, j = i & 7;
            int cc = (j < 4) ? j : (128 + j);
            int gy = ridx(gy0 + rr, H), gx = ridx(gx0 + cc, W);
            raw[rr][cc] = inA[in_off + (size_t)gy * W + gx];
        }
    } else {
        for (int i = tid; i < 40*136; i += 256) {
            int rr = i / 136, cc = i - rr*136;
            int gy = ridx(gy0 + rr, H), gx = ridx(gx0 + cc, W);
            raw[rr][cc] = inA[in_off + (size_t)gy * W + gx];
        }
    }
    __syncthreads();
    for (int i = tid; i < 40*64; i += 256) {
        int rr = i >> 6, c = i & 63;
        float s = 0.f;
        #pragma unroll
        for (int k = 0; k < 9; ++k) s = fmaf(g.w[k], raw[rr][2*c + k], s);
        mid[rr][c] = s;
    }
    __syncthreads();
    {
        int r = tid >> 6, c = tid & 63;
        int ox = x0d + c;
        #pragma unroll
        for (int j = 0; j < 4; ++j) {
            int oy = y0d + r*4 + j;
            if (oy < Hd && ox < Wd) {
                int rb = 2*(r*4 + j);
                float s = 0.f;
                #pragma unroll
                for (int k = 0; k < 9; ++k) s = fmaf(g.w[k], mid[rb + k][c], s);
                out[out_off + (size_t)oy * Wd + ox] = s;
            }
        }
    }
}

// ---------------------------------------------------------------------------
// k4pz: ALL levels' loss, z-PAIRED: one block = one 64x32 tile of z=2m AND z=2m+1
// (they share the same 5 dn planes j in [m-2,m+2]: even z uses w0,w2,w4,w6,w8;
// odd z uses w1,w3,w5,w7 on the top 4). float4 staging. Level 0: x<132 only
// (x>=132 handled in k1l0 since up==0 there).
struct K4P {
    const float* dn[5];
    const float* cur[5];
    const float* in; const float* tg;
    const __hip_bfloat16* DIFF;
    float* P;
    int use_diff;
    int bo[6];
    GW g;
};

__global__ __launch_bounds__(256)
void k4pz(K4P p)
{
    const int Dt[5] = {64,32,16,8,4}, Ht[5] = {256,128,64,32,16};
    __shared__ float vt[2][20][72];
    __shared__ float mid[2][20][64];
    const int bid = (int)blockIdx.x;
    int l = 0;
    while (l < 4 && bid >= p.bo[l+1]) ++l;
    const int local = bid - p.bo[l];
    const int D = Dt[l], H = Ht[l], W = H;
    const int Dd = D >> 1, Hd = H >> 1, Wd = W >> 1, Md = Hd * Wd;
    const int ntx = (l == 0) ? 3 : ((W + 63) >> 6);
    const int nty = (H + 31) >> 5;
    const int ntiles = ntx * nty;
    const int pairidx = local / ntiles;
    const int rem = local - pairidx * ntiles;
    const int ty = rem / ntx, tx = rem - ty * ntx;
    const int x0 = tx * 64, y0 = ty * 32;
    const int b = pairidx / Dd, m = pairidx - b * Dd;
    const int z0 = 2 * m;
    const GW g = p.g;
    const float* dn0 = p.dn[l] + (size_t)b * Dd * Md;
    const float* dn1 = p.dn[l] + (size_t)(1 - b) * Dd * Md;
    const int tid = threadIdx.x;
    const int vy0 = (y0 >> 1) - 2;

    const bool fastz = (z0 >= 4) && (z0 + 5 < D);
    if (fastz) {
        const int j0 = m - 2;      // planes j0..j0+4 all within [0, Dd)
        for (int i = tid; i < 20*18; i += 256) {
            int rr = i / 18, gg = i - rr*18;
            int vy = vy0 + rr;
            bool vyok = (vy >= 0) && (vy < Hd);
            if (gg == 0) {
                #pragma unroll
                for (int cc = 0; cc < 4; ++cc) {
                    int txx = x0 - 4 + cc;
                    if (txx < 0) txx = -1 - txx;   // left reflect lands in [0,3]
                    float e0=0.f, e1=0.f, o0=0.f, o1=0.f;
                    if (vyok && txx < Wd) {
                        size_t o = (size_t)vy * Wd + txx;
                        #pragma unroll
                        for (int t = 0; t < 5; ++t) {
                            float a  = dn0[(size_t)(j0+t)*Md + o];
                            float bb = dn1[(size_t)(j0+t)*Md + o];
                            float we = g.w[2*t];
                            e0 = fmaf(we, a, e0); e1 = fmaf(we, bb, e1);
                            if (t >= 1) {
                                float wo = g.w[2*t-1];
                                o0 = fmaf(wo, a, o0); o1 = fmaf(wo, bb, o1);
                            }
                        }
                    }
                    vt[0][rr][cc] = 8.f*(g.A*e0 + g.B*e1);
                    vt[1][rr][cc] = 8.f*(g.A*o0 + g.B*o1);
                }
            } else {
                int cc = 4 * gg;                 // 4..68
                int txx = x0 - 4 + cc;           // >= 0, 4-aligned
                if (vyok && txx + 3 < Wd) {
                    size_t o = (size_t)vy * Wd + txx;
                    float4 e0={0,0,0,0}, e1={0,0,0,0}, o0={0,0,0,0}, o1={0,0,0,0};
                    #pragma unroll
                    for (int t = 0; t < 5; ++t) {
                        float4 a  = *(const float4*)(dn0 + (size_t)(j0+t)*Md + o);
                        float4 bb = *(const float4*)(dn1 + (size_t)(j0+t)*Md + o);
                        float we = g.w[2*t];
                        e0.x=fmaf(we,a.x,e0.x); e0.y=fmaf(we,a.y,e0.y);
                        e0.z=fmaf(we,a.z,e0.z); e0.w=fmaf(we,a.w,e0.w);
                        e1.x=fmaf(we,bb.x,e1.x); e1.y=fmaf(we,bb.y,e1.y);
                        e1.z=fmaf(we,bb.z,e1.z); e1.w=fmaf(we,bb.w,e1.w);
                        if (t >= 1) {
                            float wo = g.w[2*t-1];
                            o0.x=fmaf(wo,a.x,o0.x); o0.y=fmaf(wo,a.y,o0.y);
                            o0.z=fmaf(wo,a.z,o0.z); o0.w=fmaf(wo,a.w,o0.w);
                            o1.x=fmaf(wo,bb.x,o1.x); o1.y=fmaf(wo,bb.y,o1.y);
                            o1.z=fmaf(wo,bb.z,o1.z); o1.w=fmaf(wo,bb.w,o1.w);
                        }
                    }
                    vt[0][rr][cc+0] = 8.f*(g.A*e0.x + g.B*e1.x);
                    vt[0][rr][cc+1] = 8.f*(g.A*e0.y + g.B*e1.y);
                    vt[0][rr][cc+2] = 8.f*(g.A*e0.z + g.B*e1.z);
                    vt[0][rr][cc+3] = 8.f*(g.A*e0.w + g.B*e1.w);
                    vt[1][rr][cc+0] = 8.f*(g.A*o0.x + g.B*o1.x);
                    vt[1][rr][cc+1] = 8.f*(g.A*o0.y + g.B*o1.y);
                    vt[1][rr][cc+2] = 8.f*(g.A*o0.z + g.B*o1.z);
                    vt[1][rr][cc+3] = 8.f*(g.A*o0.w + g.B*o1.w);
                } else {
                    #pragma unroll
                    for (int q4 = 0; q4 < 4; ++q4) {
                        int txq = txx + q4;
                        float e0=0.f, e1=0.f, o0=0.f, o1=0.f;
                        if (vyok && txq < Wd) {
                            size_t o = (size_t)vy * Wd + txq;
                            #pragma unroll
                            for (int t = 0; t < 5; ++t) {
                                float a  = dn0[(size_t)(j0+t)*Md + o];
                                float bb = dn1[(size_t)(j0+t)*Md + o];
                                float we = g.w[2*t];
                                e0 = fmaf(we, a, e0); e1 = fmaf(we, bb, e1);
                                if (t >= 1) {
                                    float wo = g.w[2*t-1];
                                    o0 = fmaf(wo, a, o0); o1 = fmaf(wo, bb, o1);
                                }
                            }
                        }
                        vt[0][rr][cc+q4] = 8.f*(g.A*e0 + g.B*e1);
                        vt[1][rr][cc+q4] = 8.f*(g.A*o0 + g.B*o1);
                    }
                }
            }
        }
    } else {
        // generic (edge-z or tiny level): 9-tap with reflect, per z
        for (int zz = 0; zz < 2; ++zz) {
            int z = z0 + zz;
            for (int i = tid; i < 20*72; i += 256) {
                int rr = i / 72, cc = i - rr*72;
                int vy = vy0 + rr;
                int txx = x0 - 4 + cc;
                if (txx < 0) txx = -1 - txx;
                float v = 0.f;
                if (vy >= 0 && vy < Hd && txx < Wd) {
                    size_t o = (size_t)vy * Wd + txx;
                    float s0 = 0.f, s1 = 0.f;
                    #pragma unroll
                    for (int k = 0; k < 9; ++k) {
                        int zk = ridx(z - 4 + k, D);
                        if (!(zk & 1)) {
                            int j = zk >> 1;
                            s0 = fmaf(g.w[k], dn0[(size_t)j * Md + o], s0);
                            s1 = fmaf(g.w[k], dn1[(size_t)j * Md + o], s1);
                        }
                    }
                    v = 8.f * (g.A*s0 + g.B*s1);
                }
                vt[zz][rr][cc] = v;
            }
        }
    }
    __syncthreads();
    for (int i = tid; i < 2*20*64; i += 256) {
        int zz = i / 1280;
        int r2 = i - zz*1280;
        int rr = r2 >> 6, c = r2 & 63;
        float sv = 0.f;
        #pragma unroll
        for (int k = 0; k < 9; ++k) sv = fmaf(g.w[k], vt[zz][rr][c + k], sv);
        mid[zz][rr][c] = sv;
    }
    __syncthreads();
    const bool yin = (y0 >= 4) && (y0 + 35 < H);
    const int c = tid & 63;
    const int ry_base = (tid >> 6) * 8;
    const int ox = x0 + c;
    const int xlim = (l == 0) ? 132 : W;
    const float* curl = (l >= 1) ? p.cur[l] : nullptr;
    float lsum = 0.f;
    for (int zz = 0; zz < 2; ++zz) {
        const size_t c_off = (size_t)(b*D + z0 + zz) * H * W;
        #pragma unroll
        for (int j = 0; j < 8; ++j) {
            int ry = ry_base + j;      // parity(ry) == parity(j)
            int oy = y0 + ry;
            if (ox < xlim && oy < H) {
                float sv = 0.f;
                if (yin) {
                    if (!(j & 1)) {
                        int r0 = ry >> 1;
                        sv = g.w[0]*mid[zz][r0][c] + g.w[2]*mid[zz][r0+1][c]
                           + g.w[4]*mid[zz][r0+2][c] + g.w[6]*mid[zz][r0+3][c]
                           + g.w[8]*mid[zz][r0+4][c];
                    } else {
                        int r0 = ((ry - 3) >> 1) + 2;
                        sv = g.w[1]*mid[zz][r0][c] + g.w[3]*mid[zz][r0+1][c]
                           + g.w[5]*mid[zz][r0+2][c] + g.w[7]*mid[zz][r0+3][c];
                    }
                } else {
                    #pragma unroll
                    for (int k = 0; k < 9; ++k) {
                        int gy = ridx(oy - 4 + k, H);
                        if (!(gy & 1)) sv = fmaf(g.w[k], mid[zz][(gy >> 1) - vy0][c], sv);
                    }
                }
                size_t idx = c_off + (size_t)oy * W + ox;
                float cv;
                if (l == 0) cv = p.use_diff ? __bfloat162float(p.DIFF[idx])
                                            : (p.in[idx] - p.tg[idx]);
                else        cv = curl[idx];
                lsum += fabsf(cv - sv);
            }
        }
    }
    float tot = block_sum256(lsum);
    if (tid == 0) p.P[1024 + bid] = tot / ((float)(2*D) * H * W);
}

// ---------------------------------------------------------------------------
__global__ __launch_bounds__(1024)
void kreduce(const float* __restrict__ P, int n, float* __restrict__ out)
{
    float s = 0.f;
    for (int i = threadIdx.x; i < n; i += 1024) s += P[i];
    #pragma unroll
    for (int off = 32; off > 0; off >>= 1) s += __shfl_down(s, off, 64);
    __shared__ float wp[16];
    if ((threadIdx.x & 63) == 0) wp[threadIdx.x >> 6] = s;
    __syncthreads();
    if (threadIdx.x == 0) {
        float t = 0.f;
        #pragma unroll
        for (int w = 0; w < 16; ++w) t += wp[w];
        out[0] = t;
    }
}

// ---------------------------------------------------------------------------
extern "C" void kernel_launch(void* const* d_in, const int* in_sizes, int n_in,
                              void* d_out, int out_size, void* d_ws, size_t ws_size,
                              hipStream_t stream)
{
    const float* in = (const float*)d_in[0];
    const float* tg = (const float*)d_in[1];
    float* out = (float*)d_out;

    GW g;
    {
        double u[9], S = 0.0;
        for (int k = 0; k < 9; ++k) { double d = k - 4; u[k] = exp(-0.5 * d * d); S += u[k]; }
        for (int k = 0; k < 9; ++k) g.w[k] = (float)(u[k] / S);
        g.A = (float)((2.0*u[0] + u[1] + u[3] + u[4]) / S);  // batch(2) reflect self-weight
        g.B = (float)((u[1] + 2.0*u[2] + u[3]) / S);         // cross-weight
    }

    // workspace layout (floats)
    float* T1  = (float*)d_ws;             // 2*64*128*128 = 2097152
    float* C1  = T1  + 2097152;            // 2*32*128*128 = 1048576
    float* C2  = C1  + 1048576;            // 2*16*64*64   = 131072
    float* C3  = C2  + 131072;             // 2*8*32*32    = 16384
    float* C4  = C3  + 16384;              // 2*4*16*16    = 2048
    float* C5  = C4  + 2048;               // 2*2*8*8      = 256
    float* Tl1 = C5  + 256;                // 2*32*64*64   = 262144
    float* Tl2 = Tl1 + 262144;             // 2*16*32*32   = 32768
    float* Tl3 = Tl2 + 32768;              // 2*8*16*16    = 4096
    float* Tl4 = Tl3 + 4096;               // 2*4*8*8      = 512
    float* P   = Tl4 + 512;                // 1024 (k1l0) + 1836 (k4pz) partials
    float* wend = P + 4096;
    __hip_bfloat16* DIFF = (__hip_bfloat16*)wend;
    const size_t base_bytes = (size_t)((char*)wend - (char*)d_ws);
    const size_t diff_bytes = (size_t)2 * 64 * 256 * 256 * sizeof(__hip_bfloat16);
    const int use_diff = (ws_size >= base_bytes + diff_bytes) ? 1 : 0;

    dim3 blk(256);

    // D1: level-0 WH-down of diff (+ bf16 DIFF x<132, + x>=132 partials)
    if (use_diff) k1l0<true ><<<dim3(2,8,128), blk, 0, stream>>>(in, tg, T1, DIFF, P, g);
    else          k1l0<false><<<dim3(2,8,128), blk, 0, stream>>>(in, tg, T1, nullptr, P, g);

    // D2: k2(0): T1 -> C1  (D=64, Dd=32, M4=128*128/4=4096)
    k2s<<<dim3(512), blk, 0, stream>>>(T1, C1, 64, 32, 4096, g);

    // D3-D10: small ladder (all plain, fully parallel kernels)
    k1s<<<dim3(1,4,64), blk, 0, stream>>>(C1, Tl1, 128, 128, 64, 64, g);
    k2s<<<dim3(64),     blk, 0, stream>>>(Tl1, C2, 32, 16, 1024, g);
    k1s<<<dim3(1,2,32), blk, 0, stream>>>(C2, Tl2, 64, 64, 32, 32, g);
    k2s<<<dim3(8),      blk, 0, stream>>>(Tl2, C3, 16, 8, 256, g);
    k1s<<<dim3(1,1,16), blk, 0, stream>>>(C3, Tl3, 32, 32, 16, 16, g);
    k2s<<<dim3(1),      blk, 0, stream>>>(Tl3, C4, 8, 4, 64, g);
    k1s<<<dim3(1,1,8),  blk, 0, stream>>>(C4, Tl4, 16, 16, 8, 8, g);
    k2s<<<dim3(1),      blk, 0, stream>>>(Tl4, C5, 4, 2, 16, g);

    // D11: all levels' loss, z-paired
    K4P prm;
    prm.dn[0] = C1; prm.dn[1] = C2; prm.dn[2] = C3; prm.dn[3] = C4; prm.dn[4] = C5;
    prm.cur[0] = nullptr; prm.cur[1] = C1; prm.cur[2] = C2; prm.cur[3] = C3; prm.cur[4] = C4;
    prm.in = in; prm.tg = tg;
    prm.DIFF = use_diff ? DIFF : nullptr;
    prm.P = P; prm.use_diff = use_diff;
    prm.g = g;
    // paired block counts: l0: 3*8*64=1536, l1: 2*4*32=256, l2: 1*2*16=32, l3: 8, l4: 4
    prm.bo[0] = 0; prm.bo[1] = 1536; prm.bo[2] = 1792;
    prm.bo[3] = 1824; prm.bo[4] = 1832; prm.bo[5] = 1836;
    k4pz<<<dim3(1836), blk, 0, stream>>>(prm);

    // D12: final reduce over 1024 + 1836 partials
    kreduce<<<1, 1024, 0, stream>>>(P, 1024 + 1836, out);
}

// Round 10
// 102.205 us; speedup vs baseline: 1.2008x; 1.2008x over previous
//
#include <hip/hip_runtime.h>
#include <hip/hip_bf16.h>
#include <math.h>

// Laplacian-pyramid L1 loss, (2,1,64,256,256), 5 levels, sigma=1 (9-tap), scipy-reflect.
// loss = sum_l mean |lap_pyramid(input-target)[l]| (linearity of the pyramid).
// 12 plain launches:
//   k1l0(+bf16 DIFF x<132 + x>=132 partials) -> k2s0 ->
//   FAT[k1s(1)||k3(0)] -> k2s1 -> FAT[k1s(2)||k3(1)] -> k2s2 ->
//   FAT[k1s(3)||k3(2)] -> k2s3 -> k1s(4) -> k2s4 ->
//   k4all (levels 0-2 read materialized V; levels 3-4 fused-z) -> kreduce.
// r9 lesson: keep k4 low-VGPR/low-LDS; move the z-filter into a flat float4
// kernel (V materialization) instead of scattered per-element loads.

struct GW { float w[9]; float A, B; };

__device__ __forceinline__ int ridx(int p, int n) {
    // scipy 'reflect' (symmetric) for power-of-two n; valid for p >= -2n
    int m = 2 * n;
    int q = (p + m) & (m - 1);
    return (q < n) ? q : (m - 1 - q);
}

__device__ __forceinline__ float block_sum256(float v) {
    #pragma unroll
    for (int off = 32; off > 0; off >>= 1) v += __shfl_down(v, off, 64);
    __shared__ float wp[4];
    int tid = threadIdx.x;
    if ((tid & 63) == 0) wp[tid >> 6] = v;
    __syncthreads();
    return wp[0] + wp[1] + wp[2] + wp[3];
}

// ---------------------------------------------------------------------------
// k1l0: level-0 fused W+H gaussian of (in - tg) -> T1 (even y,x).
// Also: bf16 DIFF for x<132, and the x>=132 |diff| sums as partials P[0..1024).
template<bool WDIFF>
__global__ __launch_bounds__(256)
void k1l0(const float* __restrict__ in, const float* __restrict__ tg,
          float* __restrict__ T1, __hip_bfloat16* __restrict__ DIFF,
          float* __restrict__ P, GW g)
{
    const int H = 256, W = 256, Wd = 128;
    const int x0d = blockIdx.x * 64, y0d = blockIdx.y * 16, slice = blockIdx.z;
    __shared__ float raw[40][136];
    __shared__ float mid[40][64];
    const size_t in_off  = (size_t)slice * H * W;
    const size_t out_off = (size_t)slice * 128 * 128;
    const int tid = threadIdx.x;
    const int gy0 = 2*y0d - 4, gx0 = 2*x0d - 4;
    for (int i = tid; i < 40*32; i += 256) {
        int rr = i >> 5, c4 = (i & 31) + 1;
        int gy = ridx(gy0 + rr, H);
        size_t base = in_off + (size_t)gy * W + gx0 + 4*c4;
        float4 v = *(const float4*)(in + base);
        float4 b = *(const float4*)(tg + base);
        v.x -= b.x; v.y -= b.y; v.z -= b.z; v.w -= b.w;
        *(float4*)&raw[rr][4*c4] = v;
    }
    for (int i = tid; i < 40*8; i += 256) {
        int rr = i >> 3, j = i & 7;
        int cc = (j < 4) ? j : (128 + j);
        int gy = ridx(gy0 + rr, H);
        int gx = ridx(gx0 + cc, W);
        size_t idx = in_off + (size_t)gy * W + gx;
        raw[rr][cc] = in[idx] - tg[idx];
    }
    __syncthreads();
    if (WDIFF) {
        if (blockIdx.x == 0) {
            for (int i = tid; i < 32*128; i += 256) {
                int r = i >> 7, c = i & 127;
                DIFF[in_off + (size_t)(2*y0d + r) * W + c] =
                    __float2bfloat16(raw[4 + r][4 + c]);
            }
        } else {
            for (int i = tid; i < 32*4; i += 256) {
                int r = i >> 2, c = i & 3;
                DIFF[in_off + (size_t)(2*y0d + r) * W + 128 + c] =
                    __float2bfloat16(raw[4 + r][4 + c]);
            }
        }
    }
    if (blockIdx.x == 1) {
        // x >= 132 loss contribution (up == 0 there)
        float lsum = 0.f;
        for (int i = tid; i < 32*124; i += 256) {
            int r = i / 124, c = i - r*124;
            lsum += fabsf(raw[4 + r][8 + c]);
        }
        float tot = block_sum256(lsum);
        if (tid == 0)
            P[blockIdx.y + 8*blockIdx.z] = tot * (1.f / 8388608.f);
    }
    for (int i = tid; i < 40*64; i += 256) {
        int rr = i >> 6, c = i & 63;
        float s = 0.f;
        #pragma unroll
        for (int k = 0; k < 9; ++k) s = fmaf(g.w[k], raw[rr][2*c + k], s);
        mid[rr][c] = s;
    }
    __syncthreads();
    {
        int r = tid >> 6, c = tid & 63;
        int ox = x0d + c;
        #pragma unroll
        for (int j = 0; j < 4; ++j) {
            int oy = y0d + r*4 + j;
            int rb = 2*(r*4 + j);
            float s = 0.f;
            #pragma unroll
            for (int k = 0; k < 9; ++k) s = fmaf(g.w[k], mid[rb + k][c], s);
            T1[out_off + (size_t)oy * Wd + ox] = s;
        }
    }
}

// ---------------------------------------------------------------------------
// k2s: D-axis gaussian + batch(2) reflect mix at even z. One float4/elem.
__global__ __launch_bounds__(256)
void k2s(const float* __restrict__ Tin, float* __restrict__ Cout,
         int D, int Dd, int M4, GW g)
{
    long i = (long)blockIdx.x * 256 + threadIdx.x;
    if (i >= (long)Dd * M4) return;
    int zd = (int)(i / M4);
    int q  = (int)(i - (long)zd * M4);
    const float4* T = (const float4*)Tin;
    float4* O = (float4*)Cout;
    float4 s0 = {0,0,0,0}, s1 = {0,0,0,0};
    #pragma unroll
    for (int k = 0; k < 9; ++k) {
        int zp = 2*zd - 4 + k;
        int zk = (zp >= 0 && zp < D) ? zp : ridx(zp, D);
        float4 a = T[(size_t)zk * M4 + q];
        float4 b = T[(size_t)(D + zk) * M4 + q];
        s0.x = fmaf(g.w[k], a.x, s0.x); s0.y = fmaf(g.w[k], a.y, s0.y);
        s0.z = fmaf(g.w[k], a.z, s0.z); s0.w = fmaf(g.w[k], a.w, s0.w);
        s1.x = fmaf(g.w[k], b.x, s1.x); s1.y = fmaf(g.w[k], b.y, s1.y);
        s1.z = fmaf(g.w[k], b.z, s1.z); s1.w = fmaf(g.w[k], b.w, s1.w);
    }
    float4 o0, o1;
    o0.x = g.A*s0.x + g.B*s1.x; o0.y = g.A*s0.y + g.B*s1.y;
    o0.z = g.A*s0.z + g.B*s1.z; o0.w = g.A*s0.w + g.B*s1.w;
    o1.x = g.B*s0.x + g.A*s1.x; o1.y = g.B*s0.y + g.A*s1.y;
    o1.z = g.B*s0.z + g.A*s1.z; o1.w = g.B*s0.w + g.A*s1.w;
    O[(size_t)zd * M4 + q] = o0;
    O[(size_t)(Dd + zd) * M4 + q] = o1;
}

// ---------------------------------------------------------------------------
// dev_k1_slice: fused W+H gaussian on one (H,W) slice, even (y,x) -> (Hd,Wd).
__device__ void dev_k1_slice(const float* __restrict__ inA, float* __restrict__ out,
                             int x0d, int y0d, int slice, int H, int W, int Hd, int Wd,
                             const GW& g)
{
    __shared__ float raw[40][136];
    __shared__ float mid[40][64];
    const size_t in_off  = (size_t)slice * H * W;
    const size_t out_off = (size_t)slice * Hd * Wd;
    const int tid = threadIdx.x;
    const int gy0 = 2*y0d - 4, gx0 = 2*x0d - 4;
    if (2*x0d + 127 < W) {
        for (int i = tid; i < 40*32; i += 256) {
            int rr = i >> 5, c4 = (i & 31) + 1;
            int gy = ridx(gy0 + rr, H);
            *(float4*)&raw[rr][4*c4] =
                *(const float4*)(inA + in_off + (size_t)gy * W + gx0 + 4*c4);
        }
        for (int i = tid; i < 40*8; i += 256) {
            int rr = i >> 3, j = i & 7;
            int cc = (j < 4) ? j : (128 + j);
            int gy = ridx(gy0 + rr, H), gx = ridx(gx0 + cc, W);
            raw[rr][cc] = inA[in_off + (size_t)gy * W + gx];
        }
    } else {
        for (int i = tid; i < 40*136; i += 256) {
            int rr = i / 136, cc = i - rr*136;
            int gy = ridx(gy0 + rr, H), gx = ridx(gx0 + cc, W);
            raw[rr][cc] = inA[in_off + (size_t)gy * W + gx];
        }
    }
    __syncthreads();
    for (int i = tid; i < 40*64; i += 256) {
        int rr = i >> 6, c = i & 63;
        float s = 0.f;
        #pragma unroll
        for (int k = 0; k < 9; ++k) s = fmaf(g.w[k], raw[rr][2*c + k], s);
        mid[rr][c] = s;
    }
    __syncthreads();
    {
        int r = tid >> 6, c = tid & 63;
        int ox = x0d + c;
        #pragma unroll
        for (int j = 0; j < 4; ++j) {
            int oy = y0d + r*4 + j;
            if (oy < Hd && ox < Wd) {
                int rb = 2*(r*4 + j);
                float s = 0.f;
                #pragma unroll
                for (int k = 0; k < 9; ++k) s = fmaf(g.w[k], mid[rb + k][c], s);
                out[out_off + (size_t)oy * Wd + ox] = s;
            }
        }
    }
}

__global__ __launch_bounds__(256)
void k1s(const float* __restrict__ inA, float* __restrict__ out,
         int H, int W, int Hd, int Wd, GW g)
{
    dev_k1_slice(inA, out, blockIdx.x*64, blockIdx.y*16, blockIdx.z, H, W, Hd, Wd, g);
}

// ---------------------------------------------------------------------------
// dev_k3_elem: D-filter of zero-stuffed dn + batch mix (upsample D/batch part), x8.
// V layout (2, D, Hd, Wd). Proven r2-r4.
__device__ void dev_k3_elem(long i, const float4* __restrict__ Dn, float4* __restrict__ O,
                            int D, int Dd, int M4, const GW& g)
{
    if (i >= (long)D * M4) return;
    int z = (int)(i / M4);
    int q = (int)(i - (long)z * M4);
    float4 s0 = {0,0,0,0}, s1 = {0,0,0,0};
    auto f4 = [](float4& a, float w, const float4 b) {
        a.x = fmaf(w, b.x, a.x); a.y = fmaf(w, b.y, a.y);
        a.z = fmaf(w, b.z, a.z); a.w = fmaf(w, b.w, a.w);
    };
    if (z >= 4 && z + 4 < D) {
        if ((z & 1) == 0) {
            int base = (z >> 1) - 2;
            #pragma unroll
            for (int kk = 0; kk < 5; ++kk) {
                f4(s0, g.w[2*kk], Dn[(size_t)(base + kk) * M4 + q]);
                f4(s1, g.w[2*kk], Dn[(size_t)(Dd + base + kk) * M4 + q]);
            }
        } else {
            int base = (z - 3) >> 1;
            #pragma unroll
            for (int kk = 0; kk < 4; ++kk) {
                f4(s0, g.w[2*kk+1], Dn[(size_t)(base + kk) * M4 + q]);
                f4(s1, g.w[2*kk+1], Dn[(size_t)(Dd + base + kk) * M4 + q]);
            }
        }
    } else {
        #pragma unroll
        for (int k = 0; k < 9; ++k) {
            int zk = ridx(z - 4 + k, D);
            if (!(zk & 1)) {
                int j = zk >> 1;
                f4(s0, g.w[k], Dn[(size_t)j * M4 + q]);
                f4(s1, g.w[k], Dn[(size_t)(Dd + j) * M4 + q]);
            }
        }
    }
    float4 o0, o1;
    o0.x = 8.f*(g.A*s0.x + g.B*s1.x); o0.y = 8.f*(g.A*s0.y + g.B*s1.y);
    o0.z = 8.f*(g.A*s0.z + g.B*s1.z); o0.w = 8.f*(g.A*s0.w + g.B*s1.w);
    o1.x = 8.f*(g.B*s0.x + g.A*s1.x); o1.y = 8.f*(g.B*s0.y + g.A*s1.y);
    o1.z = 8.f*(g.B*s0.z + g.A*s1.z); o1.w = 8.f*(g.B*s0.w + g.A*s1.w);
    O[(size_t)z * M4 + q] = o0;
    O[(size_t)(D + z) * M4 + q] = o1;
}

// FAT: first n1 blocks run k1s(l+1) (ntx==1 tiles); the rest run k3(l) flat.
__global__ __launch_bounds__(256)
void fatk(const float* __restrict__ k1in, float* __restrict__ k1out,
          int H, int W, int Hd, int Wd, int nty, int n1,
          const float* __restrict__ dn, float* __restrict__ V,
          int D, int Dd, int M4, GW g)
{
    if ((int)blockIdx.x < n1) {
        int ty = (int)blockIdx.x % nty, slice = (int)blockIdx.x / nty;
        dev_k1_slice(k1in, k1out, 0, ty*16, slice, H, W, Hd, Wd, g);
    } else {
        long i = (long)((int)blockIdx.x - n1)*256 + threadIdx.x;
        dev_k3_elem(i, (const float4*)dn, (float4*)V, D, Dd, M4, g);
    }
}

// ---------------------------------------------------------------------------
// k4all: all levels' loss. Levels 0-2: stage vt from materialized V (one
// coalesced load per element). Levels 3-4 (24 blocks): fused generic-z from dn.
struct K4P {
    const float* V[3];
    const float* dn34[2];   // C4, C5
    const float* cur[5];    // cur[1..4] = C1..C4
    const float* in; const float* tg;
    const __hip_bfloat16* DIFF;
    float* P;
    int use_diff;
    int bo[6];
    GW g;
};

__global__ __launch_bounds__(256)
void k4all(K4P p)
{
    const int Dt[5] = {64,32,16,8,4}, Ht[5] = {256,128,64,32,16};
    __shared__ float vt[20][72];
    __shared__ float mid[20][64];
    const int bid = (int)blockIdx.x;
    int l = 0;
    while (l < 4 && bid >= p.bo[l+1]) ++l;
    const int local = bid - p.bo[l];
    const int D = Dt[l], H = Ht[l], W = H;
    const int Dd = D >> 1, Hd = H >> 1, Wd = W >> 1, Md = Hd * Wd;
    const int ntx = (l == 0) ? 3 : ((W + 63) >> 6);
    const int nty = (H + 31) >> 5;
    const int s = local / (ntx*nty);
    const int rem = local - s*(ntx*nty);
    const int ty = rem / ntx, tx = rem - ty*ntx;
    const int x0 = tx*64, y0 = ty*32;
    const int b = s / D, z = s - b*D;
    const GW g = p.g;
    const int tid = threadIdx.x;
    const int vy0 = (y0 >> 1) - 2;

    if (l < 3) {
        // --- simple stage from V(l): (2,D,Hd,Wd), slice s ---
        const float* V = p.V[l];
        const size_t v_off = (size_t)s * Md;
        for (int i = tid; i < 20*72; i += 256) {
            int rr = i / 72, cc = i - rr*72;
            int vy = vy0 + rr;
            int txx = x0 - 4 + cc;
            if (txx < 0) txx = -1 - txx;   // left reflect lands in [0,3] < Wd
            float v = 0.f;
            if (vy >= 0 && vy < Hd && txx < Wd) v = V[v_off + (size_t)vy * Wd + txx];
            vt[rr][cc] = v;                // x >= Wd of t is zero
        }
    } else {
        // --- fused generic-z (levels 3-4 only; D<=8 so never z-interior) ---
        const float* dnb = p.dn34[l-3];
        const float* dn0 = dnb + (size_t)b * Dd * Md;
        const float* dn1 = dnb + (size_t)(1 - b) * Dd * Md;
        for (int i = tid; i < 20*72; i += 256) {
            int rr = i / 72, cc = i - rr*72;
            int vy = vy0 + rr;
            int txx = x0 - 4 + cc;
            if (txx < 0) txx = -1 - txx;
            float v = 0.f;
            if (vy >= 0 && vy < Hd && txx < Wd) {
                size_t o = (size_t)vy * Wd + txx;
                float s0 = 0.f, s1 = 0.f;
                #pragma unroll
                for (int k = 0; k < 9; ++k) {
                    int zk = ridx(z - 4 + k, D);
                    if (!(zk & 1)) {
                        int j = zk >> 1;
                        s0 = fmaf(g.w[k], dn0[(size_t)j * Md + o], s0);
                        s1 = fmaf(g.w[k], dn1[(size_t)j * Md + o], s1);
                    }
                }
                v = 8.f * (g.A*s0 + g.B*s1);
            }
            vt[rr][cc] = v;
        }
    }
    __syncthreads();
    for (int i = tid; i < 20*64; i += 256) {
        int rr = i >> 6, c = i & 63;
        float sv = 0.f;
        #pragma unroll
        for (int k = 0; k < 9; ++k) sv = fmaf(g.w[k], vt[rr][c + k], sv);
        mid[rr][c] = sv;
    }
    __syncthreads();
    const bool yin = (y0 >= 4) && (y0 + 35 < H);
    const int c = tid & 63;
    const int ry_base = (tid >> 6) * 8;
    const int ox = x0 + c;
    const int xlim = (l == 0) ? 132 : W;
    const size_t c_off = (size_t)s * H * W;
    const float* curl = (l >= 1) ? p.cur[l] : nullptr;
    float lsum = 0.f;
    #pragma unroll
    for (int j = 0; j < 8; ++j) {
        int ry = ry_base + j;          // parity(ry) == parity(j)
        int oy = y0 + ry;
        if (ox < xlim && oy < H) {
            float sv = 0.f;
            if (yin) {
                if (!(j & 1)) {
                    int r0 = ry >> 1;
                    sv = g.w[0]*mid[r0][c] + g.w[2]*mid[r0+1][c] + g.w[4]*mid[r0+2][c]
                       + g.w[6]*mid[r0+3][c] + g.w[8]*mid[r0+4][c];
                } else {
                    int r0 = ((ry - 3) >> 1) + 2;
                    sv = g.w[1]*mid[r0][c] + g.w[3]*mid[r0+1][c]
                       + g.w[5]*mid[r0+2][c] + g.w[7]*mid[r0+3][c];
                }
            } else {
                #pragma unroll
                for (int k = 0; k < 9; ++k) {
                    int gy = ridx(oy - 4 + k, H);
                    if (!(gy & 1)) sv = fmaf(g.w[k], mid[(gy >> 1) - vy0][c], sv);
                }
            }
            size_t idx = c_off + (size_t)oy * W + ox;
            float cv;
            if (l == 0) cv = p.use_diff ? __bfloat162float(p.DIFF[idx])
                                        : (p.in[idx] - p.tg[idx]);
            else        cv = curl[idx];
            lsum += fabsf(cv - sv);
        }
    }
    float tot = block_sum256(lsum);
    if (tid == 0) p.P[1024 + bid] = tot / ((float)(2*D) * H * W);
}

// ---------------------------------------------------------------------------
__global__ __launch_bounds__(1024)
void kreduce(const float* __restrict__ P, int n, float* __restrict__ out)
{
    float s = 0.f;
    for (int i = threadIdx.x; i < n; i += 1024) s += P[i];
    #pragma unroll
    for (int off = 32; off > 0; off >>= 1) s += __shfl_down(s, off, 64);
    __shared__ float wp[16];
    if ((threadIdx.x & 63) == 0) wp[threadIdx.x >> 6] = s;
    __syncthreads();
    if (threadIdx.x == 0) {
        float t = 0.f;
        #pragma unroll
        for (int w = 0; w < 16; ++w) t += wp[w];
        out[0] = t;
    }
}

// ---------------------------------------------------------------------------
extern "C" void kernel_launch(void* const* d_in, const int* in_sizes, int n_in,
                              void* d_out, int out_size, void* d_ws, size_t ws_size,
                              hipStream_t stream)
{
    const float* in = (const float*)d_in[0];
    const float* tg = (const float*)d_in[1];
    float* out = (float*)d_out;

    GW g;
    {
        double u[9], S = 0.0;
        for (int k = 0; k < 9; ++k) { double d = k - 4; u[k] = exp(-0.5 * d * d); S += u[k]; }
        for (int k = 0; k < 9; ++k) g.w[k] = (float)(u[k] / S);
        g.A = (float)((2.0*u[0] + u[1] + u[3] + u[4]) / S);  // batch(2) reflect self-weight
        g.B = (float)((u[1] + 2.0*u[2] + u[3]) / S);         // cross-weight
    }

    // workspace layout (floats)
    float* T1  = (float*)d_ws;             // 2*64*128*128 = 2097152
    float* C1  = T1  + 2097152;            // 1048576
    float* C2  = C1  + 1048576;            // 131072
    float* C3  = C2  + 131072;             // 16384
    float* C4  = C3  + 16384;              // 2048
    float* C5  = C4  + 2048;               // 256
    float* Tl1 = C5  + 256;                // 262144
    float* Tl2 = Tl1 + 262144;             // 32768
    float* Tl3 = Tl2 + 32768;              // 4096
    float* Tl4 = Tl3 + 4096;               // 512
    float* V0  = Tl4 + 512;                // 2*64*128*128 = 2097152
    float* V1  = V0  + 2097152;            // 2*32*64*64   = 262144
    float* V2  = V1  + 262144;             // 2*16*32*32   = 32768
    float* P   = V2  + 32768;              // 1024 + 3672 partials
    float* wend = P + 8192;
    __hip_bfloat16* DIFF = (__hip_bfloat16*)wend;
    const size_t base_bytes = (size_t)((char*)wend - (char*)d_ws);
    const size_t diff_bytes = (size_t)2 * 64 * 256 * 256 * sizeof(__hip_bfloat16);
    const int use_diff = (ws_size >= base_bytes + diff_bytes) ? 1 : 0;

    dim3 blk(256);

    // D1: level-0 WH-down of diff (+ bf16 DIFF x<132, + x>=132 partials)
    if (use_diff) k1l0<true ><<<dim3(2,8,128), blk, 0, stream>>>(in, tg, T1, DIFF, P, g);
    else          k1l0<false><<<dim3(2,8,128), blk, 0, stream>>>(in, tg, T1, nullptr, P, g);

    // D2: k2(0): T1 -> C1
    k2s<<<dim3(512), blk, 0, stream>>>(T1, C1, 64, 32, 4096, g);

    // D3: FAT [k1s(1): C1->Tl1, 256 blocks] || [k3(0): C1->V0, 1024 blocks]
    fatk<<<dim3(256 + 1024), blk, 0, stream>>>(C1, Tl1, 128, 128, 64, 64, 4, 256,
                                               C1, V0, 64, 32, 4096, g);
    // D4: k2(1): Tl1 -> C2
    k2s<<<dim3(64), blk, 0, stream>>>(Tl1, C2, 32, 16, 1024, g);

    // D5: FAT [k1s(2): C2->Tl2, 64] || [k3(1): C2->V1, 128]
    fatk<<<dim3(64 + 128), blk, 0, stream>>>(C2, Tl2, 64, 64, 32, 32, 2, 64,
                                             C2, V1, 32, 16, 1024, g);
    // D6: k2(2): Tl2 -> C3
    k2s<<<dim3(8), blk, 0, stream>>>(Tl2, C3, 16, 8, 256, g);

    // D7: FAT [k1s(3): C3->Tl3, 16] || [k3(2): C3->V2, 16]
    fatk<<<dim3(16 + 16), blk, 0, stream>>>(C3, Tl3, 32, 32, 16, 16, 1, 16,
                                            C3, V2, 16, 8, 256, g);
    // D8: k2(3): Tl3 -> C4
    k2s<<<dim3(1), blk, 0, stream>>>(Tl3, C4, 8, 4, 64, g);

    // D9: k1s(4): C4 -> Tl4
    k1s<<<dim3(1,1,8), blk, 0, stream>>>(C4, Tl4, 16, 16, 8, 8, g);
    // D10: k2(4): Tl4 -> C5
    k2s<<<dim3(1), blk, 0, stream>>>(Tl4, C5, 4, 2, 16, g);

    // D11: all levels' loss
    K4P prm;
    prm.V[0] = V0; prm.V[1] = V1; prm.V[2] = V2;
    prm.dn34[0] = C4; prm.dn34[1] = C5;
    prm.cur[0] = nullptr; prm.cur[1] = C1; prm.cur[2] = C2; prm.cur[3] = C3; prm.cur[4] = C4;
    prm.in = in; prm.tg = tg;
    prm.DIFF = use_diff ? DIFF : nullptr;
    prm.P = P; prm.use_diff = use_diff;
    prm.g = g;
    // blocks: l0: 3*8*128=3072, l1: 2*4*64=512, l2: 1*2*32=64, l3: 16, l4: 8
    prm.bo[0] = 0; prm.bo[1] = 3072; prm.bo[2] = 3584;
    prm.bo[3] = 3648; prm.bo[4] = 3664; prm.bo[5] = 3672;
    k4all<<<dim3(3672), blk, 0, stream>>>(prm);

    // D12: final reduce over 1024 + 3672 partials
    kreduce<<<1, 1024, 0, stream>>>(P, 1024 + 3672, out);
}